// Round 13
// baseline (274.311 us; speedup 1.0000x reference)
//
#include <hip/hip_runtime.h>
#include <hip/hip_bf16.h>
#include <math.h>

#define DIM    256
#define KCB    4096
#define NROWS  32768
#define DECAYF 0.99f
#define MARGIN 0.024f

// ---- d_out offsets (in floats) ----
#define OUT_ZQ   0
#define OUT_IDX  8388608
#define OUT_LOSS 8421376
#define OUT_PPL  8421377
#define OUT_CB   8421378
#define OUT_CS   9469954
#define OUT_ES   9474050

// ---- d_ws offsets (bytes) ----
#define WS_A2      0u            // [32768][256] bf16 (hi only) 16 MB; dead after
                                 // dist_mfma -> reused: slot[] (+0), cbT (+1MB)
#define WS_EH      33554432u     // [4096][256] bf16            2 MB
#define WS_ZSQ     35651584u     // N f32
#define WS_ESQ     35782656u     // K f32
#define WS_P1      35799040u     // [32][32768] f32 partial min1
#define WS_PI      39993344u     // [32][32768] i32 partial idx1
#define WS_P2      44187648u     // [32][32768] f32 partial min2 (dead after
                                 // merge -> reused for loss partials)
#define WS_IDX     48381952u     // N i32 final idx
#define WS_FLIST   48513024u     // N i32 flagged rows
#define WS_LIST2   48644096u     // N i32 inverted index
#define WS_BASE    48775168u     // K i32
#define WS_ZERO    48791552u     // zeroed region start
#define WS_COUNTS  48791552u     // K i32
#define WS_CURSOR  48807936u     // K i32
#define WS_FLCNT   48824320u
#define WS_ZEROLEN 32772u

#define WS_SLOT    WS_A2                 // N u64 packed (distbits<<32)|idx
#define WS_CBT     (WS_A2 + 1048576u)    // [256][4096] f32 transposed codebook

typedef __attribute__((ext_vector_type(8))) short short8;
typedef __attribute__((ext_vector_type(4))) float f32x4;

#define GLOAD(g, l) __builtin_amdgcn_global_load_lds( \
    (const __attribute__((address_space(1))) unsigned int*)(g), \
    (__attribute__((address_space(3))) unsigned int*)(l), 16, 0, 0)

__device__ __forceinline__ unsigned short f2bf(float x) {
  __hip_bfloat16 h = __float2bfloat16(x);
  return *reinterpret_cast<unsigned short*>(&h);
}

// fused: blocks [0, NROWS/4) do z -> A2 + z_sq; rest do cb -> EH + e_sq.
__global__ __launch_bounds__(256) void prep_all(
    const float* __restrict__ z, const float* __restrict__ cb,
    unsigned short* __restrict__ A2, unsigned short* __restrict__ EH,
    float* __restrict__ z_sq, float* __restrict__ e_sq) {
  int b = blockIdx.x;
  int lane = threadIdx.x & 63;
  const float* src;
  unsigned short* dst;
  float* sq;
  int gw;
  if (b < NROWS / 4) {
    gw = (b * 256 + threadIdx.x) >> 6;
    src = z; dst = A2; sq = z_sq;
  } else {
    gw = ((b - NROWS / 4) * 256 + threadIdx.x) >> 6;
    src = cb; dst = EH; sq = e_sq;
  }
  float4 v = *(const float4*)(src + (size_t)gw * DIM + lane * 4);
  float x[4] = {v.x, v.y, v.z, v.w};
  unsigned short h[4];
  float ss = 0.f;
#pragma unroll
  for (int i = 0; i < 4; ++i) { ss += x[i] * x[i]; h[i] = f2bf(x[i]); }
  *(ushort4*)(dst + (size_t)gw * 256 + lane * 4) =
      make_ushort4(h[0], h[1], h[2], h[3]);
#pragma unroll
  for (int off = 32; off > 0; off >>= 1) ss += __shfl_down(ss, off);
  if (lane == 0) sq[gw] = ss;
}

// 128x128 tile bf16 MFMA over K=256, two-phase half-K staging (64 KB LDS ->
// 2 blocks/CU).  Per block only 3 full syncs; each compute phase is a
// barrier-free run of 4 ks x {8 ds_read_b128 + 16 MFMA} the compiler can
// pipeline.  The co-resident block covers each block's exposed stage.
// Swapped operands: lane holds 16 codes in-register; argmin = in-lane scan
// + 2 shfl stages.
__global__ __launch_bounds__(256) void dist_mfma(
    const unsigned short* __restrict__ A2, const unsigned short* __restrict__ EH,
    const float* __restrict__ e_sq,
    float* __restrict__ p1, int* __restrict__ pi, float* __restrict__ p2) {
  __shared__ __align__(16) unsigned short sZ[4][128 * 32];
  __shared__ __align__(16) unsigned short sE[4][128 * 32];
  __shared__ float se[128];
  __shared__ float sm1[2][128];
  __shared__ int   smi[2][128];
  __shared__ float sm2[2][128];

  int wgid = blockIdx.x;
  int swz = (wgid & 7) * 1024 + (wgid >> 3);   // XCD-contiguous, bijective
  int rowp = swz >> 5, colp = swz & 31;
  int brow = rowp * 128, bcol = colp * 128;
  int tid = threadIdx.x;
  int lane = tid & 63, w = tid >> 6;
  int wr = w >> 1, wc = w & 1;
  int rl = lane & 15, k8 = lane >> 4;

  f32x4 acc[4][4] = {};

  int r0 = tid >> 2;
  int s_src = (tid & 3) ^ (r0 & 3) ^ ((r0 >> 2) & 3);  // involution w/ read
  const char* baseA = (const char*)A2 + (size_t)(brow + r0) * 512 + s_src * 16;
  const char* baseB = (const char*)EH + (size_t)(bcol + r0) * 512 + s_src * 16;

#define STAGE(b, ks_) do {                                                    \
    GLOAD(baseA + (ks_) * 64,         &sZ[b][tid * 8]);                       \
    GLOAD(baseA + 32768 + (ks_) * 64, &sZ[b][2048 + tid * 8]);                \
    GLOAD(baseB + (ks_) * 64,         &sE[b][tid * 8]);                       \
    GLOAD(baseB + 32768 + (ks_) * 64, &sE[b][2048 + tid * 8]);                \
  } while (0)

#define COMPUTE(bi) do {                                                      \
    const unsigned short* za = sZ[bi];                                        \
    const unsigned short* ea = sE[bi];                                        \
    short8 ef[4], zf[4];                                                      \
    _Pragma("unroll")                                                         \
    for (int mi = 0; mi < 4; ++mi)                                            \
      ef[mi] = *(const short8*)&ea[(wr * 64 + mi * 16 + rl) * 32 + sseg];     \
    _Pragma("unroll")                                                         \
    for (int ni = 0; ni < 4; ++ni)                                            \
      zf[ni] = *(const short8*)&za[(wc * 64 + ni * 16 + rl) * 32 + sseg];     \
    _Pragma("unroll")                                                         \
    for (int mi = 0; mi < 4; ++mi)                                            \
      _Pragma("unroll")                                                       \
      for (int ni = 0; ni < 4; ++ni)                                          \
        acc[mi][ni] = __builtin_amdgcn_mfma_f32_16x16x32_bf16(                \
            ef[mi], zf[ni], acc[mi][ni], 0, 0, 0);                            \
  } while (0)

  int sseg = (k8 ^ (rl & 3) ^ ((rl >> 2) & 3)) * 8;

  if (tid < 128) se[tid] = e_sq[bcol + tid];
  STAGE(0, 0); STAGE(1, 1); STAGE(2, 2); STAGE(3, 3);
  asm volatile("s_waitcnt vmcnt(0)" ::: "memory");
  __syncthreads();

  COMPUTE(0); COMPUTE(1); COMPUTE(2); COMPUTE(3);
  __syncthreads();   // all waves done reading half 0 (syncthreads drains lgkm)

  STAGE(0, 4); STAGE(1, 5); STAGE(2, 6); STAGE(3, 7);
  asm volatile("s_waitcnt vmcnt(0)" ::: "memory");
  __syncthreads();

  COMPUTE(0); COMPUTE(1); COMPUTE(2); COMPUTE(3);
#undef COMPUTE
#undef STAGE

  // e_sq for this lane's 16 in-register codes (code = cb0 + mi*16 + j)
  int cb0 = bcol + wr * 64 + k8 * 4;
  float e2l[4][4];
#pragma unroll
  for (int mi = 0; mi < 4; ++mi)
#pragma unroll
    for (int j = 0; j < 4; ++j)
      e2l[mi][j] = se[wr * 64 + mi * 16 + k8 * 4 + j];

  // per z-row (ni, rl): in-lane scan of 16 codes, then 2-stage k8 reduce
#pragma unroll
  for (int ni = 0; ni < 4; ++ni) {
    float m1 = 1e30f, m2 = 1e30f; int i1 = 0;
#pragma unroll
    for (int mi = 0; mi < 4; ++mi) {
#pragma unroll
      for (int j = 0; j < 4; ++j) {
        float q = e2l[mi][j] - 2.0f * acc[mi][ni][j];
        if (q < m1) { m2 = m1; m1 = q; i1 = cb0 + mi * 16 + j; }
        else if (q < m2) m2 = q;
      }
    }
#pragma unroll
    for (int mk = 16; mk <= 32; mk <<= 1) {
      float v1 = __shfl_xor(m1, mk);
      int   vi = __shfl_xor(i1, mk);
      float v2 = __shfl_xor(m2, mk);
      float hi = fmaxf(m1, v1), lo2 = fminf(m2, v2);
      if (v1 < m1) { m1 = v1; i1 = vi; }
      else if (v1 == m1 && vi < i1) i1 = vi;
      m2 = fminf(hi, lo2);
    }
    if (k8 == 0) {
      int rowl = wc * 64 + ni * 16 + rl;
      sm1[wr][rowl] = m1; smi[wr][rowl] = i1; sm2[wr][rowl] = m2;
    }
  }
  __syncthreads();
  if (tid < 128) {
    float a1 = sm1[0][tid]; int ai = smi[0][tid]; float a2 = sm2[0][tid];
    float b1 = sm1[1][tid]; int bi = smi[1][tid]; float b2 = sm2[1][tid];
    float m1, m2; int i1;
    if (b1 < a1) { m1 = b1; i1 = bi; m2 = fminf(a1, b2); }
    else         { m1 = a1; i1 = ai; m2 = fminf(b1, a2); }  // ties keep smaller idx
    size_t o = (size_t)colp * NROWS + (brow + tid);
    p1[o] = m1; pi[o] = i1; p2[o] = m2;
  }
}

// fused (both run after dist_mfma, A2 dead):
//   blocks [0, 128):  merge 32 panel partials per row -> packed slot
//   blocks [128, 256): cb[4096][256] -> cbT[256][4096] transpose
__global__ __launch_bounds__(256) void merge_tp(
    const float* __restrict__ p1, const int* __restrict__ pi,
    const float* __restrict__ p2, int* __restrict__ flist,
    int* __restrict__ flcnt, unsigned long long* __restrict__ slot,
    const float* __restrict__ cb, float* __restrict__ cbT) {
  __shared__ float tile[32][257];
  int b = blockIdx.x;
  int t = threadIdx.x;
  if (b < NROWS / 256) {
    int r = b * 256 + t;
    float m1 = 1e30f, m2 = 1e30f; int i1 = 0;
    for (int cbk = 0; cbk < 32; ++cbk) {
      size_t o = (size_t)cbk * NROWS + r;
      float v1 = p1[o]; int vi = pi[o]; float v2 = p2[o];
      float hi = fmaxf(m1, v1), lo2 = fminf(m2, v2);
      if (v1 < m1) { m1 = v1; i1 = vi; }
      else if (v1 == m1 && vi < i1) i1 = vi;
      m2 = fminf(hi, lo2);
    }
    if (m2 - m1 < MARGIN) {
      slot[r] = ~0ULL;
      int p = atomicAdd(flcnt, 1);
      flist[p] = r;
    } else {
      slot[r] = ((unsigned long long)__float_as_uint(m1) << 32) | (unsigned)i1;
    }
  } else {
    int c0 = (b - NROWS / 256) * 32;
    int r = t >> 6, c4 = (t & 63) * 4;
#pragma unroll
    for (int i = 0; i < 8; ++i) {
      float4 v = *(const float4*)(cb + (size_t)(c0 + r + i * 4) * DIM + c4);
      tile[r + i * 4][c4 + 0] = v.x;
      tile[r + i * 4][c4 + 1] = v.y;
      tile[r + i * 4][c4 + 2] = v.z;
      tile[r + i * 4][c4 + 3] = v.w;
    }
    __syncthreads();
    int cs = (t & 7) * 4;
#pragma unroll
    for (int j = 0; j < 8; ++j) {
      int d = (t >> 3) + j * 32;
      float4 wv = make_float4(tile[cs][d], tile[cs + 1][d],
                              tile[cs + 2][d], tile[cs + 3][d]);
      *(float4*)(cbT + (size_t)d * KCB + c0 + cs) = wv;
    }
  }
}

// exact fp32 rescore: item = (8-row batch, 1024-code quarter).
__global__ __launch_bounds__(256) void rescore_partial(
    const float* __restrict__ z, const float* __restrict__ cbT,
    const float* __restrict__ z_sq, const float* __restrict__ e_sq,
    const int* __restrict__ flist, const int* __restrict__ flcnt,
    unsigned long long* __restrict__ slot) {
  __shared__ float zs[8][256];
  __shared__ int   rid[8];
  __shared__ float zq[8];
  __shared__ unsigned long long wred[4][8];
  int t = threadIdx.x;
  int lane = t & 63, w = t >> 6;
  int cnt = *flcnt;
  int nitems = ((cnt + 7) >> 3) << 2;
  for (int it = blockIdx.x; it < nitems; it += gridDim.x) {
    int batch = it >> 2, quarter = it & 3;
    __syncthreads();
    if (t < 8) {
      int fi = batch * 8 + t;
      int rr = flist[fi < cnt ? fi : (cnt - 1)];
      rid[t] = rr; zq[t] = z_sq[rr];
    }
    __syncthreads();
    {
      int r8 = t >> 5, d0 = (t & 31) * 8;
      const float* zp = z + (size_t)rid[r8] * DIM + d0;
      *(float4*)&zs[r8][d0] = *(const float4*)(zp);
      *(float4*)&zs[r8][d0 + 4] = *(const float4*)(zp + 4);
    }
    __syncthreads();
    int cbase = quarter * 1024 + t * 4;
    float4 es4 = *(const float4*)(e_sq + cbase);
    float a0[8], a1[8], a2[8], a3[8];
#pragma unroll
    for (int r = 0; r < 8; ++r) { a0[r] = 0.f; a1[r] = 0.f; a2[r] = 0.f; a3[r] = 0.f; }
    for (int d = 0; d < DIM; ++d) {
      float4 e = *(const float4*)(cbT + (size_t)d * KCB + cbase);
#pragma unroll
      for (int r = 0; r < 8; ++r) {
        float zv = zs[r][d];
        a0[r] = fmaf(zv, e.x, a0[r]);
        a1[r] = fmaf(zv, e.y, a1[r]);
        a2[r] = fmaf(zv, e.z, a2[r]);
        a3[r] = fmaf(zv, e.w, a3[r]);
      }
    }
#pragma unroll
    for (int r = 0; r < 8; ++r) {
      float d0 = (zq[r] + es4.x) - 2.0f * a0[r];
      float d1 = (zq[r] + es4.y) - 2.0f * a1[r];
      float d2 = (zq[r] + es4.z) - 2.0f * a2[r];
      float d3 = (zq[r] + es4.w) - 2.0f * a3[r];
      float m = d0; int ci = cbase;
      if (d1 < m) { m = d1; ci = cbase + 1; }
      if (d2 < m) { m = d2; ci = cbase + 2; }
      if (d3 < m) { m = d3; ci = cbase + 3; }
      unsigned long long p =
          ((unsigned long long)__float_as_uint(m) << 32) | (unsigned)ci;
#pragma unroll
      for (int mk = 32; mk >= 1; mk >>= 1) {
        unsigned long long q = __shfl_xor(p, mk);
        if (q < p) p = q;
      }
      if (lane == 0) wred[w][r] = p;
    }
    __syncthreads();
    if (t < 8) {
      unsigned long long m = wred[0][t];
      if (wred[1][t] < m) m = wred[1][t];
      if (wred[2][t] < m) m = wred[2][t];
      if (wred[3][t] < m) m = wred[3][t];
      atomicMin(&slot[rid[t]], m);
    }
  }
}

// z_q + straight-through + loss partial + counts; unpacks idx from slot.
__global__ __launch_bounds__(256) void gather_kernel(
    const float* __restrict__ z, const float* __restrict__ cb,
    const unsigned long long* __restrict__ slot, int* __restrict__ idx,
    float* __restrict__ out_idxf, float* __restrict__ out_zq,
    int* __restrict__ counts, float* __restrict__ lossp) {
  __shared__ float ls[4];
  int gw = (blockIdx.x * 256 + threadIdx.x) >> 6;
  int lane = threadIdx.x & 63;
  int w = threadIdx.x >> 6;
  int k = (int)(unsigned)(slot[gw] & 0xFFFFFFFFu);
  float4 zq = *(const float4*)(cb + (size_t)k * DIM + lane * 4);
  float4 zv = *(const float4*)(z + (size_t)gw * DIM + lane * 4);
  float4 o;
  o.x = zv.x + (zq.x - zv.x);
  o.y = zv.y + (zq.y - zv.y);
  o.z = zv.z + (zq.z - zv.z);
  o.w = zv.w + (zq.w - zv.w);
  *(float4*)(out_zq + (size_t)gw * DIM + lane * 4) = o;
  float dx = zv.x - zq.x, dy = zv.y - zq.y, dz = zv.z - zq.z, dw = zv.w - zq.w;
  float s = dx * dx + dy * dy + dz * dz + dw * dw;
#pragma unroll
  for (int off = 32; off > 0; off >>= 1) s += __shfl_down(s, off);
  if (lane == 0) {
    ls[w] = s;
    idx[gw] = k;
    out_idxf[gw] = (float)k;
    atomicAdd(&counts[k], 1);
  }
  __syncthreads();
  if (threadIdx.x == 0)
    lossp[blockIdx.x] = ls[0] + ls[1] + ls[2] + ls[3];
}

__global__ void prefix_kernel(const int* __restrict__ counts,
                              int* __restrict__ base, int* __restrict__ cursor) {
  __shared__ int part[256];
  __shared__ int pre[256];
  int t = threadIdx.x;
  int loc[16]; int s = 0;
#pragma unroll
  for (int i = 0; i < 16; ++i) { loc[i] = counts[t * 16 + i]; s += loc[i]; }
  part[t] = s;
  __syncthreads();
  if (t == 0) { int a = 0; for (int i = 0; i < 256; ++i) { pre[i] = a; a += part[i]; } }
  __syncthreads();
  int a = pre[t];
#pragma unroll
  for (int i = 0; i < 16; ++i) { base[t * 16 + i] = a; cursor[t * 16 + i] = a; a += loc[i]; }
}

__global__ void scatter_kernel(const int* __restrict__ idx,
                               int* __restrict__ cursor, int* __restrict__ list2) {
  int n = blockIdx.x * 256 + threadIdx.x;
  int k = idx[n];
  int p = atomicAdd(&cursor[k], 1);
  list2[p] = n;
}

// per-code: sum assigned z rows (inverted index), EMA update, outputs.
// Block 0 additionally reduces loss partials + entropy.
__global__ __launch_bounds__(256) void finalize_codes(
    const float* __restrict__ ema_cs, const float* __restrict__ ema_es,
    const int* __restrict__ counts, const int* __restrict__ base,
    const int* __restrict__ list2, const float* __restrict__ z,
    float* __restrict__ out_cb, float* __restrict__ out_cs,
    float* __restrict__ out_es, const float* __restrict__ lossp,
    float* __restrict__ out_loss, float* __restrict__ out_ppl) {
  __shared__ float red[256];
  int gw = (blockIdx.x * 256 + threadIdx.x) >> 6;
  int lane = threadIdx.x & 63;
  int cnt = counts[gw], b0 = base[gw];
  float sx = 0.f, sy = 0.f, sz = 0.f, sw = 0.f;
  for (int i = 0; i < cnt; ++i) {
    int n = list2[b0 + i];
    float4 v = *(const float4*)(z + (size_t)n * DIM + lane * 4);
    sx += v.x; sy += v.y; sz += v.z; sw += v.w;
  }
  const float omd = 1.0f - DECAYF;
  float cntf = (float)cnt;
  float ncs = ema_cs[gw] * DECAYF + omd * cntf;
  float nden = ncs + 0.04096f;
  if (lane == 0) out_cs[gw] = ncs;
  size_t o = (size_t)gw * DIM + lane * 4;
  float4 em = *(const float4*)(ema_es + o);
  float nex = em.x * DECAYF + omd * sx;
  float ney = em.y * DECAYF + omd * sy;
  float nez = em.z * DECAYF + omd * sz;
  float new_ = em.w * DECAYF + omd * sw;
  *(float2*)(out_es + o) = make_float2(nex, ney);
  *(float2*)(out_es + o + 2) = make_float2(nez, new_);
  *(float2*)(out_cb + o) = make_float2(nex / nden, ney / nden);
  *(float2*)(out_cb + o + 2) = make_float2(nez / nden, new_ / nden);

  if (blockIdx.x == 0) {
    int t = threadIdx.x;
    float s = 0.f;
    for (int i = t; i < 8192; i += 256) s += lossp[i];
    float e = 0.f;
    for (int i = t; i < 4096; i += 256) {
      float p = (float)counts[i] * (1.0f / (float)NROWS);
      e -= p * logf(p + 1e-12f);
    }
    red[t] = s;
    __syncthreads();
    for (int st = 128; st > 0; st >>= 1) {
      if (t < st) red[t] += red[t + st];
      __syncthreads();
    }
    float loss_tot = red[0];
    __syncthreads();
    red[t] = e;
    __syncthreads();
    for (int st = 128; st > 0; st >>= 1) {
      if (t < st) red[t] += red[t + st];
      __syncthreads();
    }
    if (t == 0) {
      out_loss[0] = 0.25f * (loss_tot / 8388608.0f);
      out_ppl[0] = expf(red[0]);
    }
  }
}

extern "C" void kernel_launch(void* const* d_in, const int* in_sizes, int n_in,
                              void* d_out, int out_size, void* d_ws, size_t ws_size,
                              hipStream_t stream) {
  (void)in_sizes; (void)n_in; (void)out_size; (void)ws_size;
  const float* z      = (const float*)d_in[0];
  const float* cb     = (const float*)d_in[1];
  const float* ema_cs = (const float*)d_in[2];
  const float* ema_es = (const float*)d_in[3];
  float* out = (float*)d_out;
  char*  ws  = (char*)d_ws;

  unsigned short* A2 = (unsigned short*)(ws + WS_A2);
  unsigned short* EH = (unsigned short*)(ws + WS_EH);
  float* z_sq  = (float*)(ws + WS_ZSQ);
  float* e_sq  = (float*)(ws + WS_ESQ);
  float* p1    = (float*)(ws + WS_P1);
  int*   pi    = (int*)(ws + WS_PI);
  float* p2    = (float*)(ws + WS_P2);
  float* lossp = (float*)(ws + WS_P2);   // reuse: dead after merge
  unsigned long long* slot = (unsigned long long*)(ws + WS_SLOT);  // A2 reuse
  float* cbT   = (float*)(ws + WS_CBT);                            // A2 reuse
  int*   idx   = (int*)(ws + WS_IDX);
  int*   flist = (int*)(ws + WS_FLIST);
  int*   list2 = (int*)(ws + WS_LIST2);
  int*   base  = (int*)(ws + WS_BASE);
  int*   counts = (int*)(ws + WS_COUNTS);
  int*   cursor = (int*)(ws + WS_CURSOR);
  int*   flcnt  = (int*)(ws + WS_FLCNT);

  hipMemsetAsync(ws + WS_ZERO, 0, WS_ZEROLEN, stream);

  prep_all<<<NROWS / 4 + KCB / 4, 256, 0, stream>>>(z, cb, A2, EH, z_sq, e_sq);
  dist_mfma<<<(NROWS / 128) * (KCB / 128), 256, 0, stream>>>(A2, EH, e_sq,
                                                             p1, pi, p2);
  merge_tp<<<NROWS / 256 + KCB / 32, 256, 0, stream>>>(p1, pi, p2, flist,
                                                       flcnt, slot, cb, cbT);
  rescore_partial<<<2048, 256, 0, stream>>>(z, cbT, z_sq, e_sq, flist, flcnt,
                                            slot);
  gather_kernel<<<NROWS / 4, 256, 0, stream>>>(z, cb, slot, idx,
                                               out + OUT_IDX, out + OUT_ZQ,
                                               counts, lossp);
  prefix_kernel<<<1, 256, 0, stream>>>(counts, base, cursor);
  scatter_kernel<<<NROWS / 256, 256, 0, stream>>>(idx, cursor, list2);
  finalize_codes<<<KCB / 4, 256, 0, stream>>>(ema_cs, ema_es, counts, base,
                                              list2, z, out + OUT_CB,
                                              out + OUT_CS, out + OUT_ES,
                                              lossp, out + OUT_LOSS,
                                              out + OUT_PPL);
}

// Round 14
// 248.024 us; speedup vs baseline: 1.1060x; 1.1060x over previous
//
#include <hip/hip_runtime.h>
#include <hip/hip_bf16.h>
#include <math.h>

#define DIM    256
#define KCB    4096
#define NROWS  32768
#define DECAYF 0.99f
#define MARGIN 0.024f

// ---- d_out offsets (in floats) ----
#define OUT_ZQ   0
#define OUT_IDX  8388608
#define OUT_LOSS 8421376
#define OUT_PPL  8421377
#define OUT_CB   8421378
#define OUT_CS   9469954
#define OUT_ES   9474050

// ---- d_ws offsets (bytes) ----
#define WS_A2      0u            // [32768][256] bf16 (hi only) 16 MB; dead after
                                 // dist_mfma -> reused: slot[] (+0), cbT (+1MB)
#define WS_EH      33554432u     // [4096][256] bf16            2 MB
#define WS_ZSQ     35651584u     // N f32
#define WS_ESQ     35782656u     // K f32
#define WS_P1      35799040u     // [32][32768] f32 partial min1
#define WS_PI      39993344u     // [32][32768] i32 partial idx1
#define WS_P2      44187648u     // [32][32768] f32 partial min2 (dead after
                                 // merge -> reused for loss partials)
#define WS_IDX     48381952u     // N i32 final idx
#define WS_FLIST   48513024u     // N i32 flagged rows
#define WS_LIST2   48644096u     // N i32 inverted index
#define WS_BASE    48775168u     // K i32
#define WS_ZERO    48791552u     // zeroed region start
#define WS_COUNTS  48791552u     // K i32
#define WS_CURSOR  48807936u     // K i32
#define WS_FLCNT   48824320u
#define WS_ZEROLEN 32772u

#define WS_SLOT    WS_A2                 // N u64 packed (distbits<<32)|idx
#define WS_CBT     (WS_A2 + 1048576u)    // [256][4096] f32 transposed codebook

typedef __attribute__((ext_vector_type(8))) short short8;
typedef __attribute__((ext_vector_type(4))) float f32x4;

#define GLOAD(g, l) __builtin_amdgcn_global_load_lds( \
    (const __attribute__((address_space(1))) unsigned int*)(g), \
    (__attribute__((address_space(3))) unsigned int*)(l), 16, 0, 0)

__device__ __forceinline__ unsigned short f2bf(float x) {
  __hip_bfloat16 h = __float2bfloat16(x);
  return *reinterpret_cast<unsigned short*>(&h);
}

// fused: blocks [0, NROWS/4) do z -> A2 + z_sq; rest do cb -> EH + e_sq.
__global__ __launch_bounds__(256) void prep_all(
    const float* __restrict__ z, const float* __restrict__ cb,
    unsigned short* __restrict__ A2, unsigned short* __restrict__ EH,
    float* __restrict__ z_sq, float* __restrict__ e_sq) {
  int b = blockIdx.x;
  int lane = threadIdx.x & 63;
  const float* src;
  unsigned short* dst;
  float* sq;
  int gw;
  if (b < NROWS / 4) {
    gw = (b * 256 + threadIdx.x) >> 6;
    src = z; dst = A2; sq = z_sq;
  } else {
    gw = ((b - NROWS / 4) * 256 + threadIdx.x) >> 6;
    src = cb; dst = EH; sq = e_sq;
  }
  float4 v = *(const float4*)(src + (size_t)gw * DIM + lane * 4);
  float x[4] = {v.x, v.y, v.z, v.w};
  unsigned short h[4];
  float ss = 0.f;
#pragma unroll
  for (int i = 0; i < 4; ++i) { ss += x[i] * x[i]; h[i] = f2bf(x[i]); }
  *(ushort4*)(dst + (size_t)gw * 256 + lane * 4) =
      make_ushort4(h[0], h[1], h[2], h[3]);
#pragma unroll
  for (int off = 32; off > 0; off >>= 1) ss += __shfl_down(ss, off);
  if (lane == 0) sq[gw] = ss;
}

// 128x128 tile bf16 MFMA over K=256, BK=32, 3-buffer counted-vmcnt pipeline
// (r12 structure, best measured: 120 us, 3 blocks/CU).  Per iter: vmcnt(4)
// (next tile's 4 loads in flight), raw s_barrier flanked by sched_barrier(0)
// (rule-#18 hoist fence), compute, stage ks+2.
__global__ __launch_bounds__(256) void dist_mfma(
    const unsigned short* __restrict__ A2, const unsigned short* __restrict__ EH,
    const float* __restrict__ e_sq,
    float* __restrict__ p1, int* __restrict__ pi, float* __restrict__ p2) {
  __shared__ __align__(16) unsigned short sZ[3][128 * 32];
  __shared__ __align__(16) unsigned short sE[3][128 * 32];
  __shared__ float se[128];
  __shared__ float sm1[2][128];
  __shared__ int   smi[2][128];
  __shared__ float sm2[2][128];

  int wgid = blockIdx.x;
  int swz = (wgid & 7) * 1024 + (wgid >> 3);   // XCD-contiguous, bijective
  int rowp = swz >> 5, colp = swz & 31;
  int brow = rowp * 128, bcol = colp * 128;
  int tid = threadIdx.x;
  int lane = tid & 63, w = tid >> 6;
  int wr = w >> 1, wc = w & 1;
  int rl = lane & 15, k8 = lane >> 4;

  f32x4 acc[4][4] = {};

  int r0 = tid >> 2;
  int s_src = (tid & 3) ^ (r0 & 3) ^ ((r0 >> 2) & 3);  // involution w/ read
  const char* baseA = (const char*)A2 + (size_t)(brow + r0) * 512 + s_src * 16;
  const char* baseB = (const char*)EH + (size_t)(bcol + r0) * 512 + s_src * 16;

#define STAGE(b, ks_) do {                                                    \
    GLOAD(baseA + (ks_) * 64,         &sZ[b][tid * 8]);                       \
    GLOAD(baseA + 32768 + (ks_) * 64, &sZ[b][2048 + tid * 8]);                \
    GLOAD(baseB + (ks_) * 64,         &sE[b][tid * 8]);                       \
    GLOAD(baseB + 32768 + (ks_) * 64, &sE[b][2048 + tid * 8]);                \
  } while (0)

  if (tid < 128) se[tid] = e_sq[bcol + tid];
  STAGE(0, 0);
  STAGE(1, 1);
  __syncthreads();   // full drain: tiles 0,1 resident, se visible

#pragma unroll
  for (int ks = 0; ks < 8; ++ks) {
    if (ks >= 2 && ks < 7) { asm volatile("s_waitcnt vmcnt(4)" ::: "memory"); }
    if (ks == 7)           { asm volatile("s_waitcnt vmcnt(0)" ::: "memory"); }
    if (ks >= 1) {
      __builtin_amdgcn_sched_barrier(0);
      __builtin_amdgcn_s_barrier();
      __builtin_amdgcn_sched_barrier(0);
    }
    const unsigned short* za = sZ[ks % 3];
    const unsigned short* ea = sE[ks % 3];
    short8 ef[4], zf[4];
    int sseg = (k8 ^ (rl & 3) ^ ((rl >> 2) & 3)) * 8;
#pragma unroll
    for (int mi = 0; mi < 4; ++mi)
      ef[mi] = *(const short8*)&ea[(wr * 64 + mi * 16 + rl) * 32 + sseg];
#pragma unroll
    for (int ni = 0; ni < 4; ++ni)
      zf[ni] = *(const short8*)&za[(wc * 64 + ni * 16 + rl) * 32 + sseg];
#pragma unroll
    for (int mi = 0; mi < 4; ++mi)
#pragma unroll
      for (int ni = 0; ni < 4; ++ni)
        acc[mi][ni] = __builtin_amdgcn_mfma_f32_16x16x32_bf16(
            ef[mi], zf[ni], acc[mi][ni], 0, 0, 0);
    if (ks < 6) STAGE((ks + 2) % 3, ks + 2);
  }
#undef STAGE

  // e_sq for this lane's 16 in-register codes (code = cb0 + mi*16 + j)
  int cb0 = bcol + wr * 64 + k8 * 4;
  float e2l[4][4];
#pragma unroll
  for (int mi = 0; mi < 4; ++mi)
#pragma unroll
    for (int j = 0; j < 4; ++j)
      e2l[mi][j] = se[wr * 64 + mi * 16 + k8 * 4 + j];

  // per z-row (ni, rl): in-lane scan of 16 codes, then 2-stage k8 reduce
#pragma unroll
  for (int ni = 0; ni < 4; ++ni) {
    float m1 = 1e30f, m2 = 1e30f; int i1 = 0;
#pragma unroll
    for (int mi = 0; mi < 4; ++mi) {
#pragma unroll
      for (int j = 0; j < 4; ++j) {
        float q = e2l[mi][j] - 2.0f * acc[mi][ni][j];
        if (q < m1) { m2 = m1; m1 = q; i1 = cb0 + mi * 16 + j; }
        else if (q < m2) m2 = q;
      }
    }
#pragma unroll
    for (int mk = 16; mk <= 32; mk <<= 1) {
      float v1 = __shfl_xor(m1, mk);
      int   vi = __shfl_xor(i1, mk);
      float v2 = __shfl_xor(m2, mk);
      float hi = fmaxf(m1, v1), lo2 = fminf(m2, v2);
      if (v1 < m1) { m1 = v1; i1 = vi; }
      else if (v1 == m1 && vi < i1) i1 = vi;
      m2 = fminf(hi, lo2);
    }
    if (k8 == 0) {
      int rowl = wc * 64 + ni * 16 + rl;
      sm1[wr][rowl] = m1; smi[wr][rowl] = i1; sm2[wr][rowl] = m2;
    }
  }
  __syncthreads();
  if (tid < 128) {
    float a1 = sm1[0][tid]; int ai = smi[0][tid]; float a2 = sm2[0][tid];
    float b1 = sm1[1][tid]; int bi = smi[1][tid]; float b2 = sm2[1][tid];
    float m1, m2; int i1;
    if (b1 < a1) { m1 = b1; i1 = bi; m2 = fminf(a1, b2); }
    else         { m1 = a1; i1 = ai; m2 = fminf(b1, a2); }  // ties keep smaller idx
    size_t o = (size_t)colp * NROWS + (brow + tid);
    p1[o] = m1; pi[o] = i1; p2[o] = m2;
  }
}

// fused (both run after dist_mfma, A2 dead):
//   blocks [0, 128):  merge 32 panel partials per row -> packed slot
//   blocks [128, 256): cb[4096][256] -> cbT[256][4096] transpose
__global__ __launch_bounds__(256) void merge_tp(
    const float* __restrict__ p1, const int* __restrict__ pi,
    const float* __restrict__ p2, int* __restrict__ flist,
    int* __restrict__ flcnt, unsigned long long* __restrict__ slot,
    const float* __restrict__ cb, float* __restrict__ cbT) {
  __shared__ float tile[32][257];
  int b = blockIdx.x;
  int t = threadIdx.x;
  if (b < NROWS / 256) {
    int r = b * 256 + t;
    float m1 = 1e30f, m2 = 1e30f; int i1 = 0;
    for (int cbk = 0; cbk < 32; ++cbk) {
      size_t o = (size_t)cbk * NROWS + r;
      float v1 = p1[o]; int vi = pi[o]; float v2 = p2[o];
      float hi = fmaxf(m1, v1), lo2 = fminf(m2, v2);
      if (v1 < m1) { m1 = v1; i1 = vi; }
      else if (v1 == m1 && vi < i1) i1 = vi;
      m2 = fminf(hi, lo2);
    }
    if (m2 - m1 < MARGIN) {
      slot[r] = ~0ULL;
      int p = atomicAdd(flcnt, 1);
      flist[p] = r;
    } else {
      slot[r] = ((unsigned long long)__float_as_uint(m1) << 32) | (unsigned)i1;
    }
  } else {
    int c0 = (b - NROWS / 256) * 32;
    int r = t >> 6, c4 = (t & 63) * 4;
#pragma unroll
    for (int i = 0; i < 8; ++i) {
      float4 v = *(const float4*)(cb + (size_t)(c0 + r + i * 4) * DIM + c4);
      tile[r + i * 4][c4 + 0] = v.x;
      tile[r + i * 4][c4 + 1] = v.y;
      tile[r + i * 4][c4 + 2] = v.z;
      tile[r + i * 4][c4 + 3] = v.w;
    }
    __syncthreads();
    int cs = (t & 7) * 4;
#pragma unroll
    for (int j = 0; j < 8; ++j) {
      int d = (t >> 3) + j * 32;
      float4 wv = make_float4(tile[cs][d], tile[cs + 1][d],
                              tile[cs + 2][d], tile[cs + 3][d]);
      *(float4*)(cbT + (size_t)d * KCB + c0 + cs) = wv;
    }
  }
}

// exact fp32 rescore: item = (8-row batch, 1024-code quarter).
__global__ __launch_bounds__(256) void rescore_partial(
    const float* __restrict__ z, const float* __restrict__ cbT,
    const float* __restrict__ z_sq, const float* __restrict__ e_sq,
    const int* __restrict__ flist, const int* __restrict__ flcnt,
    unsigned long long* __restrict__ slot) {
  __shared__ float zs[8][256];
  __shared__ int   rid[8];
  __shared__ float zq[8];
  __shared__ unsigned long long wred[4][8];
  int t = threadIdx.x;
  int lane = t & 63, w = t >> 6;
  int cnt = *flcnt;
  int nitems = ((cnt + 7) >> 3) << 2;
  for (int it = blockIdx.x; it < nitems; it += gridDim.x) {
    int batch = it >> 2, quarter = it & 3;
    __syncthreads();
    if (t < 8) {
      int fi = batch * 8 + t;
      int rr = flist[fi < cnt ? fi : (cnt - 1)];
      rid[t] = rr; zq[t] = z_sq[rr];
    }
    __syncthreads();
    {
      int r8 = t >> 5, d0 = (t & 31) * 8;
      const float* zp = z + (size_t)rid[r8] * DIM + d0;
      *(float4*)&zs[r8][d0] = *(const float4*)(zp);
      *(float4*)&zs[r8][d0 + 4] = *(const float4*)(zp + 4);
    }
    __syncthreads();
    int cbase = quarter * 1024 + t * 4;
    float4 es4 = *(const float4*)(e_sq + cbase);
    float a0[8], a1[8], a2[8], a3[8];
#pragma unroll
    for (int r = 0; r < 8; ++r) { a0[r] = 0.f; a1[r] = 0.f; a2[r] = 0.f; a3[r] = 0.f; }
    for (int d = 0; d < DIM; ++d) {
      float4 e = *(const float4*)(cbT + (size_t)d * KCB + cbase);
#pragma unroll
      for (int r = 0; r < 8; ++r) {
        float zv = zs[r][d];
        a0[r] = fmaf(zv, e.x, a0[r]);
        a1[r] = fmaf(zv, e.y, a1[r]);
        a2[r] = fmaf(zv, e.z, a2[r]);
        a3[r] = fmaf(zv, e.w, a3[r]);
      }
    }
#pragma unroll
    for (int r = 0; r < 8; ++r) {
      float d0 = (zq[r] + es4.x) - 2.0f * a0[r];
      float d1 = (zq[r] + es4.y) - 2.0f * a1[r];
      float d2 = (zq[r] + es4.z) - 2.0f * a2[r];
      float d3 = (zq[r] + es4.w) - 2.0f * a3[r];
      float m = d0; int ci = cbase;
      if (d1 < m) { m = d1; ci = cbase + 1; }
      if (d2 < m) { m = d2; ci = cbase + 2; }
      if (d3 < m) { m = d3; ci = cbase + 3; }
      unsigned long long p =
          ((unsigned long long)__float_as_uint(m) << 32) | (unsigned)ci;
#pragma unroll
      for (int mk = 32; mk >= 1; mk >>= 1) {
        unsigned long long q = __shfl_xor(p, mk);
        if (q < p) p = q;
      }
      if (lane == 0) wred[w][r] = p;
    }
    __syncthreads();
    if (t < 8) {
      unsigned long long m = wred[0][t];
      if (wred[1][t] < m) m = wred[1][t];
      if (wred[2][t] < m) m = wred[2][t];
      if (wred[3][t] < m) m = wred[3][t];
      atomicMin(&slot[rid[t]], m);
    }
  }
}

// z_q + straight-through + loss partial + counts; unpacks idx from slot.
__global__ __launch_bounds__(256) void gather_kernel(
    const float* __restrict__ z, const float* __restrict__ cb,
    const unsigned long long* __restrict__ slot, int* __restrict__ idx,
    float* __restrict__ out_idxf, float* __restrict__ out_zq,
    int* __restrict__ counts, float* __restrict__ lossp) {
  __shared__ float ls[4];
  int gw = (blockIdx.x * 256 + threadIdx.x) >> 6;
  int lane = threadIdx.x & 63;
  int w = threadIdx.x >> 6;
  int k = (int)(unsigned)(slot[gw] & 0xFFFFFFFFu);
  float4 zq = *(const float4*)(cb + (size_t)k * DIM + lane * 4);
  float4 zv = *(const float4*)(z + (size_t)gw * DIM + lane * 4);
  float4 o;
  o.x = zv.x + (zq.x - zv.x);
  o.y = zv.y + (zq.y - zv.y);
  o.z = zv.z + (zq.z - zv.z);
  o.w = zv.w + (zq.w - zv.w);
  *(float4*)(out_zq + (size_t)gw * DIM + lane * 4) = o;
  float dx = zv.x - zq.x, dy = zv.y - zq.y, dz = zv.z - zq.z, dw = zv.w - zq.w;
  float s = dx * dx + dy * dy + dz * dz + dw * dw;
#pragma unroll
  for (int off = 32; off > 0; off >>= 1) s += __shfl_down(s, off);
  if (lane == 0) {
    ls[w] = s;
    idx[gw] = k;
    out_idxf[gw] = (float)k;
    atomicAdd(&counts[k], 1);
  }
  __syncthreads();
  if (threadIdx.x == 0)
    lossp[blockIdx.x] = ls[0] + ls[1] + ls[2] + ls[3];
}

// exclusive prefix of counts[4096] -> base/cursor, shfl wave scan (no serial)
__global__ void prefix_kernel(const int* __restrict__ counts,
                              int* __restrict__ base, int* __restrict__ cursor) {
  __shared__ int wsum[4];
  int t = threadIdx.x;
  int lane = t & 63, w = t >> 6;
  int loc[16]; int s = 0;
#pragma unroll
  for (int i = 0; i < 16; ++i) { loc[i] = counts[t * 16 + i]; s += loc[i]; }
  int x = s;
#pragma unroll
  for (int d = 1; d < 64; d <<= 1) {
    int v = __shfl_up(x, d);
    if (lane >= d) x += v;
  }
  if (lane == 63) wsum[w] = x;
  __syncthreads();
  int woff = 0;
#pragma unroll
  for (int i = 0; i < 4; ++i) woff += (i < w) ? wsum[i] : 0;
  int a = woff + x - s;   // exclusive prefix for this thread's 16 slots
#pragma unroll
  for (int i = 0; i < 16; ++i) {
    base[t * 16 + i] = a; cursor[t * 16 + i] = a; a += loc[i];
  }
}

__global__ void scatter_kernel(const int* __restrict__ idx,
                               int* __restrict__ cursor, int* __restrict__ list2) {
  int n = blockIdx.x * 256 + threadIdx.x;
  int k = idx[n];
  int p = atomicAdd(&cursor[k], 1);
  list2[p] = n;
}

// per-code: sum assigned z rows (inverted index), EMA update, outputs.
// Block 0 additionally reduces loss partials + entropy.
__global__ __launch_bounds__(256) void finalize_codes(
    const float* __restrict__ ema_cs, const float* __restrict__ ema_es,
    const int* __restrict__ counts, const int* __restrict__ base,
    const int* __restrict__ list2, const float* __restrict__ z,
    float* __restrict__ out_cb, float* __restrict__ out_cs,
    float* __restrict__ out_es, const float* __restrict__ lossp,
    float* __restrict__ out_loss, float* __restrict__ out_ppl) {
  __shared__ float red[256];
  int gw = (blockIdx.x * 256 + threadIdx.x) >> 6;
  int lane = threadIdx.x & 63;
  int cnt = counts[gw], b0 = base[gw];
  float sx = 0.f, sy = 0.f, sz = 0.f, sw = 0.f;
  for (int i = 0; i < cnt; ++i) {
    int n = list2[b0 + i];
    float4 v = *(const float4*)(z + (size_t)n * DIM + lane * 4);
    sx += v.x; sy += v.y; sz += v.z; sw += v.w;
  }
  const float omd = 1.0f - DECAYF;
  float cntf = (float)cnt;
  float ncs = ema_cs[gw] * DECAYF + omd * cntf;
  float nden = ncs + 0.04096f;
  if (lane == 0) out_cs[gw] = ncs;
  size_t o = (size_t)gw * DIM + lane * 4;
  float4 em = *(const float4*)(ema_es + o);
  float nex = em.x * DECAYF + omd * sx;
  float ney = em.y * DECAYF + omd * sy;
  float nez = em.z * DECAYF + omd * sz;
  float new_ = em.w * DECAYF + omd * sw;
  *(float2*)(out_es + o) = make_float2(nex, ney);
  *(float2*)(out_es + o + 2) = make_float2(nez, new_);
  *(float2*)(out_cb + o) = make_float2(nex / nden, ney / nden);
  *(float2*)(out_cb + o + 2) = make_float2(nez / nden, new_ / nden);

  if (blockIdx.x == 0) {
    int t = threadIdx.x;
    float s = 0.f;
    for (int i = t; i < 8192; i += 256) s += lossp[i];
    float e = 0.f;
    for (int i = t; i < 4096; i += 256) {
      float p = (float)counts[i] * (1.0f / (float)NROWS);
      e -= p * logf(p + 1e-12f);
    }
    red[t] = s;
    __syncthreads();
    for (int st = 128; st > 0; st >>= 1) {
      if (t < st) red[t] += red[t + st];
      __syncthreads();
    }
    float loss_tot = red[0];
    __syncthreads();
    red[t] = e;
    __syncthreads();
    for (int st = 128; st > 0; st >>= 1) {
      if (t < st) red[t] += red[t + st];
      __syncthreads();
    }
    if (t == 0) {
      out_loss[0] = 0.25f * (loss_tot / 8388608.0f);
      out_ppl[0] = expf(red[0]);
    }
  }
}

extern "C" void kernel_launch(void* const* d_in, const int* in_sizes, int n_in,
                              void* d_out, int out_size, void* d_ws, size_t ws_size,
                              hipStream_t stream) {
  (void)in_sizes; (void)n_in; (void)out_size; (void)ws_size;
  const float* z      = (const float*)d_in[0];
  const float* cb     = (const float*)d_in[1];
  const float* ema_cs = (const float*)d_in[2];
  const float* ema_es = (const float*)d_in[3];
  float* out = (float*)d_out;
  char*  ws  = (char*)d_ws;

  unsigned short* A2 = (unsigned short*)(ws + WS_A2);
  unsigned short* EH = (unsigned short*)(ws + WS_EH);
  float* z_sq  = (float*)(ws + WS_ZSQ);
  float* e_sq  = (float*)(ws + WS_ESQ);
  float* p1    = (float*)(ws + WS_P1);
  int*   pi    = (int*)(ws + WS_PI);
  float* p2    = (float*)(ws + WS_P2);
  float* lossp = (float*)(ws + WS_P2);   // reuse: dead after merge
  unsigned long long* slot = (unsigned long long*)(ws + WS_SLOT);  // A2 reuse
  float* cbT   = (float*)(ws + WS_CBT);                            // A2 reuse
  int*   idx   = (int*)(ws + WS_IDX);
  int*   flist = (int*)(ws + WS_FLIST);
  int*   list2 = (int*)(ws + WS_LIST2);
  int*   base  = (int*)(ws + WS_BASE);
  int*   counts = (int*)(ws + WS_COUNTS);
  int*   cursor = (int*)(ws + WS_CURSOR);
  int*   flcnt  = (int*)(ws + WS_FLCNT);

  hipMemsetAsync(ws + WS_ZERO, 0, WS_ZEROLEN, stream);

  prep_all<<<NROWS / 4 + KCB / 4, 256, 0, stream>>>(z, cb, A2, EH, z_sq, e_sq);
  dist_mfma<<<(NROWS / 128) * (KCB / 128), 256, 0, stream>>>(A2, EH, e_sq,
                                                             p1, pi, p2);
  merge_tp<<<NROWS / 256 + KCB / 32, 256, 0, stream>>>(p1, pi, p2, flist,
                                                       flcnt, slot, cb, cbT);
  rescore_partial<<<2048, 256, 0, stream>>>(z, cbT, z_sq, e_sq, flist, flcnt,
                                            slot);
  gather_kernel<<<NROWS / 4, 256, 0, stream>>>(z, cb, slot, idx,
                                               out + OUT_IDX, out + OUT_ZQ,
                                               counts, lossp);
  prefix_kernel<<<1, 256, 0, stream>>>(counts, base, cursor);
  scatter_kernel<<<NROWS / 256, 256, 0, stream>>>(idx, cursor, list2);
  finalize_codes<<<KCB / 4, 256, 0, stream>>>(ema_cs, ema_es, counts, base,
                                              list2, z, out + OUT_CB,
                                              out + OUT_CS, out + OUT_ES,
                                              lossp, out + OUT_LOSS,
                                              out + OUT_PPL);
}

// Round 15
// 239.700 us; speedup vs baseline: 1.1444x; 1.0347x over previous
//
#include <hip/hip_runtime.h>
#include <hip/hip_bf16.h>
#include <math.h>

#define DIM    256
#define KCB    4096
#define NROWS  32768
#define DECAYF 0.99f
#define MARGIN 0.024f

// ---- d_out offsets (in floats) ----
#define OUT_ZQ   0
#define OUT_IDX  8388608
#define OUT_LOSS 8421376
#define OUT_PPL  8421377
#define OUT_CB   8421378
#define OUT_CS   9469954
#define OUT_ES   9474050

// ---- d_ws offsets (bytes) ----
#define WS_A2      0u            // [32768][256] bf16 (hi only) 16 MB; dead after
                                 // dist_mfma -> reused: slot[] (+0), cbT (+1MB)
#define WS_EH      33554432u     // [4096][256] bf16            2 MB
#define WS_ZSQ     35651584u     // N f32
#define WS_ESQ     35782656u     // K f32
#define WS_P1      35799040u     // [32][32768] f32 partial min1
#define WS_PI      39993344u     // [32][32768] i32 partial idx1
#define WS_P2      44187648u     // [32][32768] f32 partial min2 (dead after
                                 // merge -> reused for loss partials)
#define WS_IDX     48381952u     // N i32 final idx
#define WS_FLIST   48513024u     // N i32 flagged rows
#define WS_LIST2   48644096u     // N i32 inverted index
#define WS_BASE    48775168u     // K i32
#define WS_ZERO    48791552u     // zeroed region start
#define WS_COUNTS  48791552u     // K i32
#define WS_CURSOR  48807936u     // K i32
#define WS_FLCNT   48824320u
#define WS_ZEROLEN 32772u

#define WS_SLOT    WS_A2                 // N u64 packed (distbits<<32)|idx
#define WS_CBT     (WS_A2 + 1048576u)    // [256][4096] f32 transposed codebook

typedef __attribute__((ext_vector_type(8))) short short8;
typedef __attribute__((ext_vector_type(4))) float f32x4;
typedef __attribute__((ext_vector_type(2))) float f32x2;

#define GLOAD(g, l) __builtin_amdgcn_global_load_lds( \
    (const __attribute__((address_space(1))) unsigned int*)(g), \
    (__attribute__((address_space(3))) unsigned int*)(l), 16, 0, 0)

__device__ __forceinline__ unsigned short f2bf(float x) {
  __hip_bfloat16 h = __float2bfloat16(x);
  return *reinterpret_cast<unsigned short*>(&h);
}

// fused: blocks [0, NROWS/4) do z -> A2 + z_sq; rest do cb -> EH + e_sq.
__global__ __launch_bounds__(256) void prep_all(
    const float* __restrict__ z, const float* __restrict__ cb,
    unsigned short* __restrict__ A2, unsigned short* __restrict__ EH,
    float* __restrict__ z_sq, float* __restrict__ e_sq) {
  int b = blockIdx.x;
  int lane = threadIdx.x & 63;
  const float* src;
  unsigned short* dst;
  float* sq;
  int gw;
  if (b < NROWS / 4) {
    gw = (b * 256 + threadIdx.x) >> 6;
    src = z; dst = A2; sq = z_sq;
  } else {
    gw = ((b - NROWS / 4) * 256 + threadIdx.x) >> 6;
    src = cb; dst = EH; sq = e_sq;
  }
  float4 v = *(const float4*)(src + (size_t)gw * DIM + lane * 4);
  float x[4] = {v.x, v.y, v.z, v.w};
  unsigned short h[4];
  float ss = 0.f;
#pragma unroll
  for (int i = 0; i < 4; ++i) { ss += x[i] * x[i]; h[i] = f2bf(x[i]); }
  *(ushort4*)(dst + (size_t)gw * 256 + lane * 4) =
      make_ushort4(h[0], h[1], h[2], h[3]);
#pragma unroll
  for (int off = 32; off > 0; off >>= 1) ss += __shfl_down(ss, off);
  if (lane == 0) sq[gw] = ss;
}

// 128x128 tile bf16 MFMA over K=256, BK=32, 3-buffer counted-vmcnt pipeline
// (r12/r14 structure, best measured: 120 us, 3 blocks/CU).
__global__ __launch_bounds__(256) void dist_mfma(
    const unsigned short* __restrict__ A2, const unsigned short* __restrict__ EH,
    const float* __restrict__ e_sq,
    float* __restrict__ p1, int* __restrict__ pi, float* __restrict__ p2) {
  __shared__ __align__(16) unsigned short sZ[3][128 * 32];
  __shared__ __align__(16) unsigned short sE[3][128 * 32];
  __shared__ float se[128];
  __shared__ float sm1[2][128];
  __shared__ int   smi[2][128];
  __shared__ float sm2[2][128];

  int wgid = blockIdx.x;
  int swz = (wgid & 7) * 1024 + (wgid >> 3);   // XCD-contiguous, bijective
  int rowp = swz >> 5, colp = swz & 31;
  int brow = rowp * 128, bcol = colp * 128;
  int tid = threadIdx.x;
  int lane = tid & 63, w = tid >> 6;
  int wr = w >> 1, wc = w & 1;
  int rl = lane & 15, k8 = lane >> 4;

  f32x4 acc[4][4] = {};

  int r0 = tid >> 2;
  int s_src = (tid & 3) ^ (r0 & 3) ^ ((r0 >> 2) & 3);  // involution w/ read
  const char* baseA = (const char*)A2 + (size_t)(brow + r0) * 512 + s_src * 16;
  const char* baseB = (const char*)EH + (size_t)(bcol + r0) * 512 + s_src * 16;

#define STAGE(b, ks_) do {                                                    \
    GLOAD(baseA + (ks_) * 64,         &sZ[b][tid * 8]);                       \
    GLOAD(baseA + 32768 + (ks_) * 64, &sZ[b][2048 + tid * 8]);                \
    GLOAD(baseB + (ks_) * 64,         &sE[b][tid * 8]);                       \
    GLOAD(baseB + 32768 + (ks_) * 64, &sE[b][2048 + tid * 8]);                \
  } while (0)

  if (tid < 128) se[tid] = e_sq[bcol + tid];
  STAGE(0, 0);
  STAGE(1, 1);
  __syncthreads();   // full drain: tiles 0,1 resident, se visible

#pragma unroll
  for (int ks = 0; ks < 8; ++ks) {
    if (ks >= 2 && ks < 7) { asm volatile("s_waitcnt vmcnt(4)" ::: "memory"); }
    if (ks == 7)           { asm volatile("s_waitcnt vmcnt(0)" ::: "memory"); }
    if (ks >= 1) {
      __builtin_amdgcn_sched_barrier(0);
      __builtin_amdgcn_s_barrier();
      __builtin_amdgcn_sched_barrier(0);
    }
    const unsigned short* za = sZ[ks % 3];
    const unsigned short* ea = sE[ks % 3];
    short8 ef[4], zf[4];
    int sseg = (k8 ^ (rl & 3) ^ ((rl >> 2) & 3)) * 8;
#pragma unroll
    for (int mi = 0; mi < 4; ++mi)
      ef[mi] = *(const short8*)&ea[(wr * 64 + mi * 16 + rl) * 32 + sseg];
#pragma unroll
    for (int ni = 0; ni < 4; ++ni)
      zf[ni] = *(const short8*)&za[(wc * 64 + ni * 16 + rl) * 32 + sseg];
#pragma unroll
    for (int mi = 0; mi < 4; ++mi)
#pragma unroll
      for (int ni = 0; ni < 4; ++ni)
        acc[mi][ni] = __builtin_amdgcn_mfma_f32_16x16x32_bf16(
            ef[mi], zf[ni], acc[mi][ni], 0, 0, 0);
    if (ks < 6) STAGE((ks + 2) % 3, ks + 2);
  }
#undef STAGE

  // e_sq for this lane's 16 in-register codes (code = cb0 + mi*16 + j)
  int cb0 = bcol + wr * 64 + k8 * 4;
  float e2l[4][4];
#pragma unroll
  for (int mi = 0; mi < 4; ++mi)
#pragma unroll
    for (int j = 0; j < 4; ++j)
      e2l[mi][j] = se[wr * 64 + mi * 16 + k8 * 4 + j];

  // per z-row (ni, rl): in-lane scan of 16 codes, then 2-stage k8 reduce
#pragma unroll
  for (int ni = 0; ni < 4; ++ni) {
    float m1 = 1e30f, m2 = 1e30f; int i1 = 0;
#pragma unroll
    for (int mi = 0; mi < 4; ++mi) {
#pragma unroll
      for (int j = 0; j < 4; ++j) {
        float q = e2l[mi][j] - 2.0f * acc[mi][ni][j];
        if (q < m1) { m2 = m1; m1 = q; i1 = cb0 + mi * 16 + j; }
        else if (q < m2) m2 = q;
      }
    }
#pragma unroll
    for (int mk = 16; mk <= 32; mk <<= 1) {
      float v1 = __shfl_xor(m1, mk);
      int   vi = __shfl_xor(i1, mk);
      float v2 = __shfl_xor(m2, mk);
      float hi = fmaxf(m1, v1), lo2 = fminf(m2, v2);
      if (v1 < m1) { m1 = v1; i1 = vi; }
      else if (v1 == m1 && vi < i1) i1 = vi;
      m2 = fminf(hi, lo2);
    }
    if (k8 == 0) {
      int rowl = wc * 64 + ni * 16 + rl;
      sm1[wr][rowl] = m1; smi[wr][rowl] = i1; sm2[wr][rowl] = m2;
    }
  }
  __syncthreads();
  if (tid < 128) {
    float a1 = sm1[0][tid]; int ai = smi[0][tid]; float a2 = sm2[0][tid];
    float b1 = sm1[1][tid]; int bi = smi[1][tid]; float b2 = sm2[1][tid];
    float m1, m2; int i1;
    if (b1 < a1) { m1 = b1; i1 = bi; m2 = fminf(a1, b2); }
    else         { m1 = a1; i1 = ai; m2 = fminf(b1, a2); }  // ties keep smaller idx
    size_t o = (size_t)colp * NROWS + (brow + tid);
    p1[o] = m1; pi[o] = i1; p2[o] = m2;
  }
}

// fused (both run after dist_mfma, A2 dead):
//   blocks [0, 128):  merge 32 panel partials per row -> packed slot
//   blocks [128, 256): cb[4096][256] -> cbT[256][4096] transpose
__global__ __launch_bounds__(256) void merge_tp(
    const float* __restrict__ p1, const int* __restrict__ pi,
    const float* __restrict__ p2, int* __restrict__ flist,
    int* __restrict__ flcnt, unsigned long long* __restrict__ slot,
    const float* __restrict__ cb, float* __restrict__ cbT) {
  __shared__ float tile[32][257];
  int b = blockIdx.x;
  int t = threadIdx.x;
  if (b < NROWS / 256) {
    int r = b * 256 + t;
    float m1 = 1e30f, m2 = 1e30f; int i1 = 0;
    for (int cbk = 0; cbk < 32; ++cbk) {
      size_t o = (size_t)cbk * NROWS + r;
      float v1 = p1[o]; int vi = pi[o]; float v2 = p2[o];
      float hi = fmaxf(m1, v1), lo2 = fminf(m2, v2);
      if (v1 < m1) { m1 = v1; i1 = vi; }
      else if (v1 == m1 && vi < i1) i1 = vi;
      m2 = fminf(hi, lo2);
    }
    if (m2 - m1 < MARGIN) {
      slot[r] = ~0ULL;
      int p = atomicAdd(flcnt, 1);
      flist[p] = r;
    } else {
      slot[r] = ((unsigned long long)__float_as_uint(m1) << 32) | (unsigned)i1;
    }
  } else {
    int c0 = (b - NROWS / 256) * 32;
    int r = t >> 6, c4 = (t & 63) * 4;
#pragma unroll
    for (int i = 0; i < 8; ++i) {
      float4 v = *(const float4*)(cb + (size_t)(c0 + r + i * 4) * DIM + c4);
      tile[r + i * 4][c4 + 0] = v.x;
      tile[r + i * 4][c4 + 1] = v.y;
      tile[r + i * 4][c4 + 2] = v.z;
      tile[r + i * 4][c4 + 3] = v.w;
    }
    __syncthreads();
    int cs = (t & 7) * 4;
#pragma unroll
    for (int j = 0; j < 8; ++j) {
      int d = (t >> 3) + j * 32;
      float4 wv = make_float4(tile[cs][d], tile[cs + 1][d],
                              tile[cs + 2][d], tile[cs + 3][d]);
      *(float4*)(cbT + (size_t)d * KCB + c0 + cs) = wv;
    }
  }
}

// exact fp32 rescore: item = (8-row batch, 1024-code quarter).
// f32x2-packed accumulators -> v_pk_fma_f32 (2x fp32 FMA rate).
__global__ __launch_bounds__(256) void rescore_partial(
    const float* __restrict__ z, const float* __restrict__ cbT,
    const float* __restrict__ z_sq, const float* __restrict__ e_sq,
    const int* __restrict__ flist, const int* __restrict__ flcnt,
    unsigned long long* __restrict__ slot) {
  __shared__ float zs[8][256];
  __shared__ int   rid[8];
  __shared__ float zq[8];
  __shared__ unsigned long long wred[4][8];
  int t = threadIdx.x;
  int lane = t & 63, w = t >> 6;
  int cnt = *flcnt;
  int nitems = ((cnt + 7) >> 3) << 2;
  for (int it = blockIdx.x; it < nitems; it += gridDim.x) {
    int batch = it >> 2, quarter = it & 3;
    __syncthreads();
    if (t < 8) {
      int fi = batch * 8 + t;
      int rr = flist[fi < cnt ? fi : (cnt - 1)];
      rid[t] = rr; zq[t] = z_sq[rr];
    }
    __syncthreads();
    {
      int r8 = t >> 5, d0 = (t & 31) * 8;
      const float* zp = z + (size_t)rid[r8] * DIM + d0;
      *(float4*)&zs[r8][d0] = *(const float4*)(zp);
      *(float4*)&zs[r8][d0 + 4] = *(const float4*)(zp + 4);
    }
    __syncthreads();
    int cbase = quarter * 1024 + t * 4;
    float4 es4 = *(const float4*)(e_sq + cbase);
    f32x2 a01[8], a23[8];
#pragma unroll
    for (int r = 0; r < 8; ++r) {
      a01[r] = (f32x2){0.f, 0.f};
      a23[r] = (f32x2){0.f, 0.f};
    }
    for (int d = 0; d < DIM; ++d) {
      float4 e = *(const float4*)(cbT + (size_t)d * KCB + cbase);
      f32x2 e01 = (f32x2){e.x, e.y};
      f32x2 e23 = (f32x2){e.z, e.w};
#pragma unroll
      for (int r = 0; r < 8; ++r) {
        float zv = zs[r][d];
        f32x2 zz = (f32x2){zv, zv};
        a01[r] += zz * e01;   // -ffp-contract=fast -> v_pk_fma_f32
        a23[r] += zz * e23;
      }
    }
#pragma unroll
    for (int r = 0; r < 8; ++r) {
      float d0 = (zq[r] + es4.x) - 2.0f * a01[r][0];
      float d1 = (zq[r] + es4.y) - 2.0f * a01[r][1];
      float d2 = (zq[r] + es4.z) - 2.0f * a23[r][0];
      float d3 = (zq[r] + es4.w) - 2.0f * a23[r][1];
      float m = d0; int ci = cbase;
      if (d1 < m) { m = d1; ci = cbase + 1; }
      if (d2 < m) { m = d2; ci = cbase + 2; }
      if (d3 < m) { m = d3; ci = cbase + 3; }
      unsigned long long p =
          ((unsigned long long)__float_as_uint(m) << 32) | (unsigned)ci;
#pragma unroll
      for (int mk = 32; mk >= 1; mk >>= 1) {
        unsigned long long q = __shfl_xor(p, mk);
        if (q < p) p = q;
      }
      if (lane == 0) wred[w][r] = p;
    }
    __syncthreads();
    if (t < 8) {
      unsigned long long m = wred[0][t];
      if (wred[1][t] < m) m = wred[1][t];
      if (wred[2][t] < m) m = wred[2][t];
      if (wred[3][t] < m) m = wred[3][t];
      atomicMin(&slot[rid[t]], m);
    }
  }
}

// z_q + straight-through + loss partial + counts; unpacks idx from slot.
__global__ __launch_bounds__(256) void gather_kernel(
    const float* __restrict__ z, const float* __restrict__ cb,
    const unsigned long long* __restrict__ slot, int* __restrict__ idx,
    float* __restrict__ out_idxf, float* __restrict__ out_zq,
    int* __restrict__ counts, float* __restrict__ lossp) {
  __shared__ float ls[4];
  int gw = (blockIdx.x * 256 + threadIdx.x) >> 6;
  int lane = threadIdx.x & 63;
  int w = threadIdx.x >> 6;
  int k = (int)(unsigned)(slot[gw] & 0xFFFFFFFFu);
  float4 zq = *(const float4*)(cb + (size_t)k * DIM + lane * 4);
  float4 zv = *(const float4*)(z + (size_t)gw * DIM + lane * 4);
  float4 o;
  o.x = zv.x + (zq.x - zv.x);
  o.y = zv.y + (zq.y - zv.y);
  o.z = zv.z + (zq.z - zv.z);
  o.w = zv.w + (zq.w - zv.w);
  *(float4*)(out_zq + (size_t)gw * DIM + lane * 4) = o;
  float dx = zv.x - zq.x, dy = zv.y - zq.y, dz = zv.z - zq.z, dw = zv.w - zq.w;
  float s = dx * dx + dy * dy + dz * dz + dw * dw;
#pragma unroll
  for (int off = 32; off > 0; off >>= 1) s += __shfl_down(s, off);
  if (lane == 0) {
    ls[w] = s;
    idx[gw] = k;
    out_idxf[gw] = (float)k;
    atomicAdd(&counts[k], 1);
  }
  __syncthreads();
  if (threadIdx.x == 0)
    lossp[blockIdx.x] = ls[0] + ls[1] + ls[2] + ls[3];
}

// exclusive prefix of counts[4096] -> base/cursor, shfl wave scan (no serial)
__global__ void prefix_kernel(const int* __restrict__ counts,
                              int* __restrict__ base, int* __restrict__ cursor) {
  __shared__ int wsum[4];
  int t = threadIdx.x;
  int lane = t & 63, w = t >> 6;
  int loc[16]; int s = 0;
#pragma unroll
  for (int i = 0; i < 16; ++i) { loc[i] = counts[t * 16 + i]; s += loc[i]; }
  int x = s;
#pragma unroll
  for (int d = 1; d < 64; d <<= 1) {
    int v = __shfl_up(x, d);
    if (lane >= d) x += v;
  }
  if (lane == 63) wsum[w] = x;
  __syncthreads();
  int woff = 0;
#pragma unroll
  for (int i = 0; i < 4; ++i) woff += (i < w) ? wsum[i] : 0;
  int a = woff + x - s;   // exclusive prefix for this thread's 16 slots
#pragma unroll
  for (int i = 0; i < 16; ++i) {
    base[t * 16 + i] = a; cursor[t * 16 + i] = a; a += loc[i];
  }
}

__global__ void scatter_kernel(const int* __restrict__ idx,
                               int* __restrict__ cursor, int* __restrict__ list2) {
  int n = blockIdx.x * 256 + threadIdx.x;
  int k = idx[n];
  int p = atomicAdd(&cursor[k], 1);
  list2[p] = n;
}

// per-code: sum assigned z rows (inverted index), EMA update, outputs.
// Block 0 additionally reduces loss partials + entropy.
__global__ __launch_bounds__(256) void finalize_codes(
    const float* __restrict__ ema_cs, const float* __restrict__ ema_es,
    const int* __restrict__ counts, const int* __restrict__ base,
    const int* __restrict__ list2, const float* __restrict__ z,
    float* __restrict__ out_cb, float* __restrict__ out_cs,
    float* __restrict__ out_es, const float* __restrict__ lossp,
    float* __restrict__ out_loss, float* __restrict__ out_ppl) {
  __shared__ float red[256];
  int gw = (blockIdx.x * 256 + threadIdx.x) >> 6;
  int lane = threadIdx.x & 63;
  int cnt = counts[gw], b0 = base[gw];
  float sx = 0.f, sy = 0.f, sz = 0.f, sw = 0.f;
  for (int i = 0; i < cnt; ++i) {
    int n = list2[b0 + i];
    float4 v = *(const float4*)(z + (size_t)n * DIM + lane * 4);
    sx += v.x; sy += v.y; sz += v.z; sw += v.w;
  }
  const float omd = 1.0f - DECAYF;
  float cntf = (float)cnt;
  float ncs = ema_cs[gw] * DECAYF + omd * cntf;
  float nden = ncs + 0.04096f;
  if (lane == 0) out_cs[gw] = ncs;
  size_t o = (size_t)gw * DIM + lane * 4;
  float4 em = *(const float4*)(ema_es + o);
  float nex = em.x * DECAYF + omd * sx;
  float ney = em.y * DECAYF + omd * sy;
  float nez = em.z * DECAYF + omd * sz;
  float new_ = em.w * DECAYF + omd * sw;
  *(float2*)(out_es + o) = make_float2(nex, ney);
  *(float2*)(out_es + o + 2) = make_float2(nez, new_);
  *(float2*)(out_cb + o) = make_float2(nex / nden, ney / nden);
  *(float2*)(out_cb + o + 2) = make_float2(nez / nden, new_ / nden);

  if (blockIdx.x == 0) {
    int t = threadIdx.x;
    float s = 0.f;
    for (int i = t; i < 8192; i += 256) s += lossp[i];
    float e = 0.f;
    for (int i = t; i < 4096; i += 256) {
      float p = (float)counts[i] * (1.0f / (float)NROWS);
      e -= p * logf(p + 1e-12f);
    }
    red[t] = s;
    __syncthreads();
    for (int st = 128; st > 0; st >>= 1) {
      if (t < st) red[t] += red[t + st];
      __syncthreads();
    }
    float loss_tot = red[0];
    __syncthreads();
    red[t] = e;
    __syncthreads();
    for (int st = 128; st > 0; st >>= 1) {
      if (t < st) red[t] += red[t + st];
      __syncthreads();
    }
    if (t == 0) {
      out_loss[0] = 0.25f * (loss_tot / 8388608.0f);
      out_ppl[0] = expf(red[0]);
    }
  }
}

extern "C" void kernel_launch(void* const* d_in, const int* in_sizes, int n_in,
                              void* d_out, int out_size, void* d_ws, size_t ws_size,
                              hipStream_t stream) {
  (void)in_sizes; (void)n_in; (void)out_size; (void)ws_size;
  const float* z      = (const float*)d_in[0];
  const float* cb     = (const float*)d_in[1];
  const float* ema_cs = (const float*)d_in[2];
  const float* ema_es = (const float*)d_in[3];
  float* out = (float*)d_out;
  char*  ws  = (char*)d_ws;

  unsigned short* A2 = (unsigned short*)(ws + WS_A2);
  unsigned short* EH = (unsigned short*)(ws + WS_EH);
  float* z_sq  = (float*)(ws + WS_ZSQ);
  float* e_sq  = (float*)(ws + WS_ESQ);
  float* p1    = (float*)(ws + WS_P1);
  int*   pi    = (int*)(ws + WS_PI);
  float* p2    = (float*)(ws + WS_P2);
  float* lossp = (float*)(ws + WS_P2);   // reuse: dead after merge
  unsigned long long* slot = (unsigned long long*)(ws + WS_SLOT);  // A2 reuse
  float* cbT   = (float*)(ws + WS_CBT);                            // A2 reuse
  int*   idx   = (int*)(ws + WS_IDX);
  int*   flist = (int*)(ws + WS_FLIST);
  int*   list2 = (int*)(ws + WS_LIST2);
  int*   base  = (int*)(ws + WS_BASE);
  int*   counts = (int*)(ws + WS_COUNTS);
  int*   cursor = (int*)(ws + WS_CURSOR);
  int*   flcnt  = (int*)(ws + WS_FLCNT);

  hipMemsetAsync(ws + WS_ZERO, 0, WS_ZEROLEN, stream);

  prep_all<<<NROWS / 4 + KCB / 4, 256, 0, stream>>>(z, cb, A2, EH, z_sq, e_sq);
  dist_mfma<<<(NROWS / 128) * (KCB / 128), 256, 0, stream>>>(A2, EH, e_sq,
                                                             p1, pi, p2);
  merge_tp<<<NROWS / 256 + KCB / 32, 256, 0, stream>>>(p1, pi, p2, flist,
                                                       flcnt, slot, cb, cbT);
  rescore_partial<<<2048, 256, 0, stream>>>(z, cbT, z_sq, e_sq, flist, flcnt,
                                            slot);
  gather_kernel<<<NROWS / 4, 256, 0, stream>>>(z, cb, slot, idx,
                                               out + OUT_IDX, out + OUT_ZQ,
                                               counts, lossp);
  prefix_kernel<<<1, 256, 0, stream>>>(counts, base, cursor);
  scatter_kernel<<<NROWS / 256, 256, 0, stream>>>(idx, cursor, list2);
  finalize_codes<<<KCB / 4, 256, 0, stream>>>(ema_cs, ema_es, counts, base,
                                              list2, z, out + OUT_CB,
                                              out + OUT_CS, out + OUT_ES,
                                              lossp, out + OUT_LOSS,
                                              out + OUT_PPL);
}